// Round 7
// baseline (778.363 us; speedup 1.0000x reference)
//
#include <hip/hip_runtime.h>

// ---------------------------------------------------------------------------
// ChannelAttentionLayer on MI355X (gfx950). Input dtype (fp32 vs bf16) is
// DETECTED ON DEVICE (k_detect); core pipeline is bf16 MFMA + fp32 accumulate.
// R6->R7 (pipeline round): gemm_bt K-loop restructured to ping-pong
// double-buffered LDS: prefetch tile k+1 (global_load_lds) into buf^1 BEFORE
// computing tile k; ONE barrier per iteration, placed so the vmcnt drain
// covers a load that had the whole MFMA phase to land. Old structure exposed
// full load latency every iteration (scores: 12 iters, 295 TF vs conv3x3's
// >620 TF at 108 iters with the same kernel). LDS 32->64 KB, lb(256,2).
// Everything else identical to passing R6.
// ---------------------------------------------------------------------------

typedef unsigned short u16;
typedef __attribute__((ext_vector_type(8))) short bf16x8;
typedef __attribute__((ext_vector_type(4))) float f32x4;

__device__ __forceinline__ u16 f2bf(float f) {
  unsigned u = __float_as_uint(f);
  u += 0x7fffu + ((u >> 16) & 1u);
  return (u16)(u >> 16);
}
__device__ __forceinline__ float bf2f(u16 h) {
  return __uint_as_float(((unsigned)h) << 16);
}
__device__ __forceinline__ float ldin(const void* p, size_t i, int f32) {
  return f32 ? ((const float*)p)[i] : bf2f(((const u16*)p)[i]);
}
__device__ __forceinline__ void gld16(const void* g, void* l) {
  __builtin_amdgcn_global_load_lds(
      (const __attribute__((address_space(1))) unsigned int*)g,
      (__attribute__((address_space(3))) unsigned int*)l, 16, 0, 0);
}

// ---- 1) dtype detection on Wq (low 16 bits of each u32 word) ----
__global__ __launch_bounds__(256) void k_detect(const unsigned* __restrict__ w,
                                                int* __restrict__ flag) {
  __shared__ int red[4];
  int tid = threadIdx.x, cnt = 0;
  for (int i = tid; i < 65536; i += 256) {
    unsigned e = (w[i] >> 7) & 0xFFu;
    cnt += (e >= 118u && e <= 127u) ? 1 : 0;
  }
#pragma unroll
  for (int off = 32; off; off >>= 1) cnt += __shfl_down(cnt, off);
  if ((tid & 63) == 0) red[tid >> 6] = cnt;
  __syncthreads();
  if (tid == 0)
    flag[0] = (red[0] + red[1] + red[2] + red[3] < 20000) ? 1 : 0;  // 1 = fp32
}

// ---- 2) pad+transpose(+split) x ----
__global__ __launch_bounds__(256) void k_txp(const void* __restrict__ x,
                                             const int* __restrict__ flag,
                                             u16* __restrict__ xbTp) {
  __shared__ float tile[32][33];
  int f32 = flag[0];
  int b = blockIdx.z, p0 = blockIdx.x * 32, c0 = blockIdx.y * 32;
  int tx = threadIdx.x, ty = threadIdx.y;
#pragma unroll
  for (int i = 0; i < 4; i++) {
    int c = c0 + ty + i * 8, pp = p0 + tx;
    float v = 0.f;
    if (pp < 4356) {
      int yy = pp / 66, xx = pp - yy * 66;
      if (yy >= 1 && yy <= 64 && xx >= 1 && xx <= 64)
        v = ldin(x, ((size_t)b * 256 + c) * 4096 + (yy - 1) * 64 + (xx - 1), f32);
    }
    tile[ty + i * 8][tx] = v;
  }
  __syncthreads();
#pragma unroll
  for (int i = 0; i < 4; i++) {
    int pp = p0 + ty + i * 8;
    if (pp >= 4356) continue;
    int c = c0 + tx;
    float v = tile[tx][ty + i * 8];
    u16 h = f2bf(v);
    if (f32) {
      size_t base = ((size_t)b * 4356 + pp) * 768;
      xbTp[base + c] = h;
      xbTp[base + 256 + c] = f2bf(v - bf2f(h));
      xbTp[base + 512 + c] = h;
    } else {
      xbTp[((size_t)b * 4356 + pp) * 256 + c] = h;
    }
  }
}

// ---- 3) weight reorders ----
__global__ __launch_bounds__(256) void k_wq(const void* __restrict__ Wq,
                                            const int* __restrict__ flag,
                                            u16* __restrict__ WqB) {
  int f32 = flag[0];
  int Ktot = f32 ? 6912 : 2304, CBl = f32 ? 768 : 256;
  int idx = blockIdx.x * 256 + threadIdx.x;
  if (idx >= 256 * Ktot) return;
  int oc = idx / Ktot, rem = idx - oc * Ktot;
  int tap = rem / CBl, j = rem - tap * CBl;
  int part = j >> 8, c = j & 255;
  float w = ldin(Wq, oc * 2304 + c * 9 + tap, f32);
  u16 h = f2bf(w);
  WqB[idx] = (part == 2) ? f2bf(w - bf2f(h)) : h;
}
__global__ __launch_bounds__(256) void k_wkv(const void* __restrict__ Wk,
                                             const void* __restrict__ Wv,
                                             const int* __restrict__ flag,
                                             u16* __restrict__ WkvB) {
  int f32 = flag[0];
  int Ktot = f32 ? 768 : 256;
  int idx = blockIdx.x * 256 + threadIdx.x;
  if (idx >= 512 * Ktot) return;
  int m = idx / Ktot, j = idx - m * Ktot;
  int part = j >> 8, c = j & 255;
  float w = (m < 256) ? ldin(Wk, m * 256 + c, f32)
                      : ldin(Wv, (m - 256) * 256 + c, f32);
  u16 h = f2bf(w);
  WkvB[idx] = (part == 2) ? f2bf(w - bf2f(h)) : h;
}

// ---- GEMM: C[M][N] = A[M][K] . Bt[N][K]^T ----
// Ping-pong double-buffered: stage(k+1 -> buf^1) issued before compute(buf),
// one barrier/iteration. Staging: global_load_lds width 16, XOR-swizzled
// packed LDS (LDS(r,c) = G(r, c^(r&7)); frag reads 2-way = free).
// IMC: B rows are implicit-im2col reads of xbTp (tap = tapBase + kt/CB).
// EPI 0: fp32 store at C+cOff.  EPI 1: fp32 atomicAdd at C (split-K partials).
// SWZ 1: tm banded per XCD (sw1 = tm tiles/XCD). SWZ 2: tn banded per XCD
// (sw1 = total tm tiles, sw2 = tn tiles/XCD). SWZ 0: (bx,by), kChunk from bz.
template <bool IMC, int EPI, int SWZ>
__global__ __launch_bounds__(256, 2) void gemm_bt(
    const u16* __restrict__ A, const u16* __restrict__ Bt, void* __restrict__ Cptr,
    const int* __restrict__ flag, int M, int N, int Kbf, int Kf32, int ldB,
    int tapBase, long long cOff, int kChunk, int sw1, int sw2) {
  __shared__ u16 lA[2][128 * 64];
  __shared__ u16 lB[2][128 * 64];
  const int f32m = flag[0];
  const int K = f32m ? Kf32 : Kbf;
  const int CB = f32m ? 768 : 256;
  int tm, tn;
  if (SWZ == 1) {
    int lin = blockIdx.x, xcd = lin & 7, per = lin >> 3;
    tm = xcd * sw1 + (per % sw1);
    tn = per / sw1;
  } else if (SWZ == 2) {
    int lin = blockIdx.x, xcd = lin & 7, per = lin >> 3;
    tm = per % sw1;
    tn = xcd * sw2 + per / sw1;
  } else {
    tm = blockIdx.x;
    tn = blockIdx.y;
  }
  int k0 = 0, k1 = K;
  if (kChunk) {
    k0 = blockIdx.z * kChunk;
    k1 = min(k0 + kChunk, K);
  }
  const int tid = threadIdx.x, wave = tid >> 6, lane = tid & 63;
  const int sr = lane >> 3;         // source row within 8-row issue group
  const int scw = (lane & 7) ^ sr;  // XOR-swizzled source chunk
  const int wm = (wave >> 1) * 64, wn = (wave & 1) * 64;
  const int r16 = lane & 15, q = lane >> 4;
  const u16* gA = A + (size_t)(tm * 128 + wave * 32 + sr) * K + scw * 8;
  const u16* gB = nullptr;
  int pyI[4], pxI[4];
  size_t bOffI[4];
  if (IMC) {
#pragma unroll
    for (int i = 0; i < 4; i++) {
      int n = tn * 128 + wave * 32 + i * 8 + sr;  // global output pixel
      int bb = n >> 12, pix = n & 4095;
      pyI[i] = pix >> 6;
      pxI[i] = pix & 63;
      bOffI[i] = (size_t)bb * 4356;
    }
  } else {
    gB = Bt + (size_t)(tn * 128 + wave * 32 + sr) * ldB + scw * 8;
  }
  f32x4 acc[4][4] = {};

  // stage tile at kt into buffer buf (all async gld16, no waits here)
  auto stage = [&](int kt, int buf) {
    int dy = 0, dx = 0, chunk = 0;
    if (IMC) {
      int t0 = kt / CB;
      chunk = kt - t0 * CB;
      int tap = tapBase + t0;
      dy = tap / 3;
      dx = tap - dy * 3;
    }
#pragma unroll
    for (int i = 0; i < 4; i++) {
      gld16(gA + (size_t)(i * 8) * K + kt, &lA[buf][(wave * 32 + i * 8) * 64]);
      if (IMC) {
        int spix = (pyI[i] + dy) * 66 + pxI[i] + dx;
        gld16(Bt + (bOffI[i] + spix) * CB + chunk + scw * 8,
              &lB[buf][(wave * 32 + i * 8) * 64]);
      } else {
        gld16(gB + (size_t)(i * 8) * ldB + kt,
              &lB[buf][(wave * 32 + i * 8) * 64]);
      }
    }
  };

  if (k0 < k1) {
    stage(k0, 0);
    __syncthreads();  // drain prologue stage
    int flip = 0;
    for (int kt = k0; kt < k1; kt += 64) {
      if (kt + 64 < k1) stage(kt + 64, flip ^ 1);  // async prefetch
#pragma unroll
      for (int ks = 0; ks < 64; ks += 32) {
        bf16x8 af[4], bfr[4];
#pragma unroll
        for (int f = 0; f < 4; f++) {
          int ma = wm + f * 16 + r16;
          int g = (ks >> 3) + q;
          af[f] = *(const bf16x8*)&lA[flip][ma * 64 + ((g ^ (ma & 7)) << 3)];
          int nb = wn + f * 16 + r16;
          bfr[f] = *(const bf16x8*)&lB[flip][nb * 64 + ((g ^ (nb & 7)) << 3)];
        }
#pragma unroll
        for (int fi = 0; fi < 4; fi++)
#pragma unroll
          for (int fj = 0; fj < 4; fj++)
            acc[fi][fj] = __builtin_amdgcn_mfma_f32_16x16x32_bf16(
                af[fi], bfr[fj], acc[fi][fj], 0, 0, 0);
      }
      __syncthreads();  // prefetch landed + this tile's LDS reads done
      flip ^= 1;
    }
  }

  const int colB = tn * 128 + wn + r16;
  const int rowB = tm * 128 + wm + q * 4;
  if (EPI == 0) {
    float* C = (float*)Cptr + cOff;
#pragma unroll
    for (int fi = 0; fi < 4; fi++)
#pragma unroll
      for (int r = 0; r < 4; r++) {
        size_t ro = (size_t)(rowB + fi * 16 + r) * N;
#pragma unroll
        for (int fj = 0; fj < 4; fj++) C[ro + colB + fj * 16] = acc[fi][fj][r];
      }
  } else {
    float* C = (float*)Cptr + cOff;
#pragma unroll
    for (int fi = 0; fi < 4; fi++)
#pragma unroll
      for (int r = 0; r < 4; r++) {
        size_t ro = (size_t)(rowB + fi * 16 + r) * N;
#pragma unroll
        for (int fj = 0; fj < 4; fj++)
          atomicAdd(&C[ro + colB + fj * 16], acc[fi][fj][r]);
      }
  }
}

// ---- 5) BN stats (biases cancel; K/V border conv-value 0, count 17424) ----
__global__ __launch_bounds__(256) void k_stats(
    const float* __restrict__ bufQ, const float* __restrict__ bufKV,
    const void* __restrict__ gq, const void* __restrict__ betaq,
    const void* __restrict__ gk, const void* __restrict__ betak,
    const void* __restrict__ gv, const void* __restrict__ betav,
    const int* __restrict__ flag, float* __restrict__ nrm) {
  int f32 = flag[0];
  int ch = blockIdx.x, t = blockIdx.y, tid = threadIdx.x;
  const float* row = (t == 0) ? bufQ + (size_t)ch * 16384
                              : bufKV + (size_t)(t == 1 ? ch : 256 + ch) * 16384;
  float s = 0.f, ss = 0.f;
  for (int i = tid; i < 16384; i += 256) {
    float v = row[i];
    s += v;
    ss += v * v;
  }
#pragma unroll
  for (int off = 32; off; off >>= 1) {
    s += __shfl_down(s, off);
    ss += __shfl_down(ss, off);
  }
  __shared__ float ls[4], lss[4];
  if ((tid & 63) == 0) {
    ls[tid >> 6] = s;
    lss[tid >> 6] = ss;
  }
  __syncthreads();
  if (tid == 0) {
    s = ls[0] + ls[1] + ls[2] + ls[3];
    ss = lss[0] + lss[1] + lss[2] + lss[3];
    float cnt = (t == 0) ? 16384.f : 17424.f;
    float mean = s / cnt;
    float var = fmaxf(ss / cnt - mean * mean, 0.f);  // NaN-proof
    const void* g = (t == 0) ? gq : (t == 1 ? gk : gv);
    const void* be = (t == 0) ? betaq : (t == 1 ? betak : betav);
    float sc = ldin(g, ch, f32) * rsqrtf(var + 1e-5f);
    nrm[(t * 256 + ch) * 2] = sc;
    nrm[(t * 256 + ch) * 2 + 1] = ldin(be, ch, f32) - mean * sc;
  }
}

// ---- 6) normalize + hi/lo split + transpose ----
__global__ __launch_bounds__(256) void k_qTs(const float* __restrict__ bufQ,
                                             const float* __restrict__ nrm,
                                             u16* __restrict__ qTs) {
  __shared__ u16 th[32][33], tl[32][33];
  int b = blockIdx.z, q0 = blockIdx.x * 32, c0 = blockIdx.y * 32;
  int tx = threadIdx.x, ty = threadIdx.y;
#pragma unroll
  for (int i = 0; i < 4; i++) {
    int c = c0 + ty + i * 8;
    float sc = nrm[c * 2], sh = nrm[c * 2 + 1];
    float v = bufQ[(size_t)c * 16384 + b * 4096 + q0 + tx] * sc + sh;
    u16 h = f2bf(v);
    th[ty + i * 8][tx] = h;
    tl[ty + i * 8][tx] = f2bf(v - bf2f(h));
  }
  __syncthreads();
#pragma unroll
  for (int i = 0; i < 4; i++) {
    size_t base = ((size_t)b * 4096 + q0 + ty + i * 8) * 768;
    u16 h = th[tx][ty + i * 8], l = tl[tx][ty + i * 8];
    qTs[base + c0 + tx] = h;  // [hi | lo | hi]
    qTs[base + 256 + c0 + tx] = l;
    qTs[base + 512 + c0 + tx] = h;
  }
}
__global__ __launch_bounds__(256) void k_kTs(const float* __restrict__ bufKV,
                                             const float* __restrict__ nrm,
                                             u16* __restrict__ kTs) {
  __shared__ u16 th[32][33], tl[32][33];
  int b = blockIdx.z, k0 = blockIdx.x * 32, c0 = blockIdx.y * 32;
  int tx = threadIdx.x, ty = threadIdx.y;
#pragma unroll
  for (int i = 0; i < 4; i++) {
    int c = c0 + ty + i * 8;
    int kt = k0 + tx;
    float v = 0.f;
    if (kt < 4356) {
      float sc = nrm[(256 + c) * 2], sh = nrm[(256 + c) * 2 + 1];
      int yy = kt / 66, xx = kt - yy * 66;
      if (yy >= 1 && yy <= 64 && xx >= 1 && xx <= 64)
        v = bufKV[(size_t)c * 16384 + b * 4096 + (yy - 1) * 64 + (xx - 1)] * sc + sh;
      else
        v = sh;  // border: conv value 0
    }
    u16 h = f2bf(v);
    th[ty + i * 8][tx] = h;
    tl[ty + i * 8][tx] = f2bf(v - bf2f(h));
  }
  __syncthreads();
#pragma unroll
  for (int i = 0; i < 4; i++) {
    size_t base = ((size_t)b * 4480 + k0 + ty + i * 8) * 768;
    u16 h = th[tx][ty + i * 8], l = tl[tx][ty + i * 8];
    kTs[base + c0 + tx] = h;  // [hi | hi | lo]
    kTs[base + 256 + c0 + tx] = h;
    kTs[base + 512 + c0 + tx] = l;
  }
}

// ---- 7) normalized V, [b][c][4480], pads zero ----
__global__ __launch_bounds__(256) void k_vP(const float* __restrict__ bufKV,
                                            const float* __restrict__ nrm,
                                            u16* __restrict__ vP) {
  int b = blockIdx.z, ch = blockIdx.y;
  int kt = blockIdx.x * 256 + threadIdx.x;
  if (kt >= 4480) return;
  float v = 0.f;
  if (kt < 4356) {
    float sc = nrm[(512 + ch) * 2], sh = nrm[(512 + ch) * 2 + 1];
    int yy = kt / 66, xx = kt - yy * 66;
    if (yy >= 1 && yy <= 64 && xx >= 1 && xx <= 64)
      v = bufKV[(size_t)(256 + ch) * 16384 + b * 4096 + (yy - 1) * 64 + (xx - 1)] * sc + sh;
    else
      v = sh;
  }
  vP[((size_t)b * 256 + ch) * 4480 + kt] = f2bf(v);
}

// ---- 8) softmax over kt: bf16 p written IN PLACE over St (ld 8960 u16) ----
__global__ __launch_bounds__(256) void k_softmax(float* __restrict__ St,
                                                 float* __restrict__ sumP) {
  __shared__ float row[4480];
  __shared__ float red[4], red2[4];
  int qt = blockIdx.x, tid = threadIdx.x;
  float* srow = St + (size_t)qt * 4480;
  float m = -3.0e38f;
  for (int kt = tid; kt < 4480; kt += 256) {
    float v = srow[kt];
    row[kt] = v;
    if (kt < 4356) m = fmaxf(m, v);
  }
#pragma unroll
  for (int off = 32; off; off >>= 1) m = fmaxf(m, __shfl_down(m, off));
  if ((tid & 63) == 0) red[tid >> 6] = m;
  __syncthreads();  // all srow reads complete before in-place writes
  m = fmaxf(fmaxf(red[0], red[1]), fmaxf(red[2], red[3]));
  u16* prow = (u16*)srow;
  float psum = 0.f;
  for (int kt = tid; kt < 4480; kt += 256) {
    u16 h = 0;
    if (kt < 4356) {
      float p = __expf(fminf(row[kt] - m, 0.f));  // in (0,1], NaN-proof
      h = f2bf(p);
      psum += bf2f(h);
    }
    prow[kt] = h;
  }
#pragma unroll
  for (int off = 32; off; off >>= 1) psum += __shfl_down(psum, off);
  if ((tid & 63) == 0) red2[tid >> 6] = psum;
  __syncthreads();
  if (tid == 0) sumP[qt] = red2[0] + red2[1] + red2[2] + red2[3];  // >= 1
}

// ---- 9) split-K support ----
__global__ __launch_bounds__(256) void k_zeroacc(float* __restrict__ accF) {
  accF[blockIdx.x * 256 + threadIdx.x] = 0.f;
}
__global__ __launch_bounds__(256) void k_final(const float* __restrict__ accF,
                                               const float* __restrict__ sumP,
                                               const int* __restrict__ flag,
                                               void* __restrict__ out,
                                               long long cOff) {
  int idx = blockIdx.x * 256 + threadIdx.x;  // 256*4096 per batch
  int qt = idx & 4095;
  float v = accF[idx] / sumP[qt];  // sumP >= 1
  v = (v == v) ? v : 0.f;          // NaN scrub: keep failures diagnostic
  if (flag[0])
    ((float*)out)[cOff + idx] = v;
  else
    ((u16*)out)[cOff + idx] = f2bf(v);
}

// ---------------------------------------------------------------------------
extern "C" void kernel_launch(void* const* d_in, const int* in_sizes, int n_in,
                              void* d_out, int out_size, void* d_ws, size_t ws_size,
                              hipStream_t stream) {
  const void* x = d_in[0];
  const void* Wq = d_in[1];
  const void* gq = d_in[3];
  const void* betaq = d_in[4];
  const void* Wk = d_in[5];
  const void* gk = d_in[7];
  const void* betak = d_in[8];
  const void* Wv = d_in[9];
  const void* gv = d_in[11];
  const void* betav = d_in[12];

  char* ws = (char*)d_ws;
  int* flag = (int*)ws;                         // 256 B
  // Region A (dead after preprocessing; overlaid by St/accF):
  u16* xbTp = (u16*)(ws + 256);                 // 26,763,264
  u16* WqB = (u16*)(ws + 26763520);             //  3,538,944
  u16* WkvB = (u16*)(ws + 30302464);            //    786,432
  float* bufQ = (float*)(ws + 31088896);        // 16,777,216
  float* bufKV = (float*)(ws + 47866112);       // 33,554,432 -> A ends 81,420,544
  float* St = (float*)(ws + 256);               // 73,400,320 overlay -> 73,400,576
  float* accF = (float*)(ws + 73400576);        //  4,194,304 overlay -> 77,594,880
  // Region B (persistent through attention):
  u16* qTs = (u16*)(ws + 81420544);             // 25,165,824
  u16* kTs = (u16*)(ws + 106586368);            // 27,525,120
  u16* vP = (u16*)(ws + 134111488);             //  9,175,040
  float* nrm = (float*)(ws + 143286528);        //      6,144
  float* sumP4 = (float*)(ws + 143292672);      //     65,536 -> total 143,358,208

  dim3 b32x8(32, 8);
  k_detect<<<1, 256, 0, stream>>>((const unsigned*)Wq, flag);
  k_txp<<<dim3(137, 8, 4), b32x8, 0, stream>>>(x, flag, xbTp);
  k_wq<<<6912, 256, 0, stream>>>(Wq, flag, WqB);
  k_wkv<<<1536, 256, 0, stream>>>(Wk, Wv, flag, WkvB);
  // conv3x3: split-K x3 (chunk 2304) into zeroed bufQ; grid 256x3 = 768 blocks.
  // Per z: 8 XCD x (2 tm x 16 tn-band). bf16 mode: z>0 is empty-range, adds 0.
  k_zeroacc<<<16384, 256, 0, stream>>>(bufQ);
  gemm_bt<true, 1, 2><<<dim3(256, 1, 3), 256, 0, stream>>>(
      WqB, xbTp, bufQ, flag, 256, 16384, 2304, 6912, 0, 0, 0, 2304, 2, 16);
  // conv1x1: grid 512 = 8 XCD x (4 tm x 16 tn-band)
  gemm_bt<true, 0, 2><<<512, 256, 0, stream>>>(
      WkvB, xbTp, bufKV, flag, 512, 16384, 256, 768, 0, 4, 0, 0, 4, 16);
  k_stats<<<dim3(256, 3), 256, 0, stream>>>(bufQ, bufKV, gq, betaq, gk, betak,
                                            gv, betav, flag, nrm);
  k_qTs<<<dim3(128, 8, 4), b32x8, 0, stream>>>(bufQ, nrm, qTs);
  k_kTs<<<dim3(140, 8, 4), b32x8, 0, stream>>>(bufKV, nrm, kTs);
  k_vP<<<dim3(18, 256, 4), 256, 0, stream>>>(bufKV, nrm, vP);
  for (int b = 0; b < 4; b++) {
    // scores: grid 1120 = 8 XCD x (4 tm-band x 35 tn); K=768 split GEMM
    gemm_bt<false, 0, 1><<<1120, 256, 0, stream>>>(
        qTs + (size_t)b * 4096 * 768, kTs + (size_t)b * 4480 * 768, St, flag,
        4096, 4480, 768, 768, 768, 0, 0, 0, 4, 0);
    k_softmax<<<4096, 256, 0, stream>>>(St, sumP4 + b * 4096);
    k_zeroacc<<<4096, 256, 0, stream>>>(accF);
    // PV: M=256,N=4096,K=4480 split-K x7 (chunk 640), fp32 atomic partials
    gemm_bt<false, 1, 0><<<dim3(2, 32, 7), 256, 0, stream>>>(
        vP + (size_t)b * 256 * 4480, (const u16*)St, accF, flag,
        256, 4096, 4480, 4480, 8960, 0, 0, 640, 0, 0);
    k_final<<<4096, 256, 0, stream>>>(accF, sumP4 + (size_t)b * 4096, flag,
                                      d_out, (long long)b * 1048576);
  }
}

// Round 9
// 731.238 us; speedup vs baseline: 1.0644x; 1.0644x over previous
//
#include <hip/hip_runtime.h>

// ---------------------------------------------------------------------------
// ChannelAttentionLayer on MI355X (gfx950). Input dtype (fp32 vs bf16) is
// DETECTED ON DEVICE (k_detect); core pipeline is bf16 MFMA + fp32 accumulate.
// R8->R9: REVERT scores split to 3-term K=768 (2-term's k-rounding cost
// absmax 0.16 > 0.102 threshold; 3-term is 0.03125). KEEP R6 single-buffered
// 3-blocks/CU gemm_bt (best measured) and R8's phase-batched attention
// (structurally validated in R8): if ws_size >= 372,316,416 run all 4 batches
// per phase in single dispatches (tail absorption); else per-batch loop
// (R6-identical layout).
// ---------------------------------------------------------------------------

typedef unsigned short u16;
typedef __attribute__((ext_vector_type(8))) short bf16x8;
typedef __attribute__((ext_vector_type(4))) float f32x4;

__device__ __forceinline__ u16 f2bf(float f) {
  unsigned u = __float_as_uint(f);
  u += 0x7fffu + ((u >> 16) & 1u);
  return (u16)(u >> 16);
}
__device__ __forceinline__ float bf2f(u16 h) {
  return __uint_as_float(((unsigned)h) << 16);
}
__device__ __forceinline__ float ldin(const void* p, size_t i, int f32) {
  return f32 ? ((const float*)p)[i] : bf2f(((const u16*)p)[i]);
}
__device__ __forceinline__ void gld16(const void* g, void* l) {
  __builtin_amdgcn_global_load_lds(
      (const __attribute__((address_space(1))) unsigned int*)g,
      (__attribute__((address_space(3))) unsigned int*)l, 16, 0, 0);
}

// ---- 1) dtype detection on Wq (low 16 bits of each u32 word) ----
__global__ __launch_bounds__(256) void k_detect(const unsigned* __restrict__ w,
                                                int* __restrict__ flag) {
  __shared__ int red[4];
  int tid = threadIdx.x, cnt = 0;
  for (int i = tid; i < 65536; i += 256) {
    unsigned e = (w[i] >> 7) & 0xFFu;
    cnt += (e >= 118u && e <= 127u) ? 1 : 0;
  }
#pragma unroll
  for (int off = 32; off; off >>= 1) cnt += __shfl_down(cnt, off);
  if ((tid & 63) == 0) red[tid >> 6] = cnt;
  __syncthreads();
  if (tid == 0)
    flag[0] = (red[0] + red[1] + red[2] + red[3] < 20000) ? 1 : 0;  // 1 = fp32
}

// ---- 2) pad+transpose(+split) x ----
__global__ __launch_bounds__(256) void k_txp(const void* __restrict__ x,
                                             const int* __restrict__ flag,
                                             u16* __restrict__ xbTp) {
  __shared__ float tile[32][33];
  int f32 = flag[0];
  int b = blockIdx.z, p0 = blockIdx.x * 32, c0 = blockIdx.y * 32;
  int tx = threadIdx.x, ty = threadIdx.y;
#pragma unroll
  for (int i = 0; i < 4; i++) {
    int c = c0 + ty + i * 8, pp = p0 + tx;
    float v = 0.f;
    if (pp < 4356) {
      int yy = pp / 66, xx = pp - yy * 66;
      if (yy >= 1 && yy <= 64 && xx >= 1 && xx <= 64)
        v = ldin(x, ((size_t)b * 256 + c) * 4096 + (yy - 1) * 64 + (xx - 1), f32);
    }
    tile[ty + i * 8][tx] = v;
  }
  __syncthreads();
#pragma unroll
  for (int i = 0; i < 4; i++) {
    int pp = p0 + ty + i * 8;
    if (pp >= 4356) continue;
    int c = c0 + tx;
    float v = tile[tx][ty + i * 8];
    u16 h = f2bf(v);
    if (f32) {
      size_t base = ((size_t)b * 4356 + pp) * 768;
      xbTp[base + c] = h;
      xbTp[base + 256 + c] = f2bf(v - bf2f(h));
      xbTp[base + 512 + c] = h;
    } else {
      xbTp[((size_t)b * 4356 + pp) * 256 + c] = h;
    }
  }
}

// ---- 3) weight reorders ----
__global__ __launch_bounds__(256) void k_wq(const void* __restrict__ Wq,
                                            const int* __restrict__ flag,
                                            u16* __restrict__ WqB) {
  int f32 = flag[0];
  int Ktot = f32 ? 6912 : 2304, CBl = f32 ? 768 : 256;
  int idx = blockIdx.x * 256 + threadIdx.x;
  if (idx >= 256 * Ktot) return;
  int oc = idx / Ktot, rem = idx - oc * Ktot;
  int tap = rem / CBl, j = rem - tap * CBl;
  int part = j >> 8, c = j & 255;
  float w = ldin(Wq, oc * 2304 + c * 9 + tap, f32);
  u16 h = f2bf(w);
  WqB[idx] = (part == 2) ? f2bf(w - bf2f(h)) : h;
}
__global__ __launch_bounds__(256) void k_wkv(const void* __restrict__ Wk,
                                             const void* __restrict__ Wv,
                                             const int* __restrict__ flag,
                                             u16* __restrict__ WkvB) {
  int f32 = flag[0];
  int Ktot = f32 ? 768 : 256;
  int idx = blockIdx.x * 256 + threadIdx.x;
  if (idx >= 512 * Ktot) return;
  int m = idx / Ktot, j = idx - m * Ktot;
  int part = j >> 8, c = j & 255;
  float w = (m < 256) ? ldin(Wk, m * 256 + c, f32)
                      : ldin(Wv, (m - 256) * 256 + c, f32);
  u16 h = f2bf(w);
  WkvB[idx] = (part == 2) ? f2bf(w - bf2f(h)) : h;
}

// ---- GEMM: C[M][N] = A[M][K] . Bt[N][K]^T  (R6 single-buffered structure) ----
// Staging: global_load_lds width 16, XOR-swizzled packed LDS
// (LDS(r,c) = G(r, c^(r&7)); frag reads 2-way = free).
// IMC: B rows are implicit-im2col reads of xbTp (tap = tapBase + kt/CB).
// EPI 0: fp32 store at C+cOff+b*zC.  EPI 1: fp32 atomicAdd (split-K partials).
// SWZ 1: tm banded per XCD (sw1 = tm tiles/XCD), batch b = blockIdx.y.
// SWZ 2: tn banded per XCD (sw1 = tm tiles, sw2 = tn tiles/XCD), kz = bz.
// SWZ 0: (bx,by) tiles; blockIdx.z = b*nSplit + kz (split-K, batched).
template <bool IMC, int EPI, int SWZ>
__global__ __launch_bounds__(256, 3) void gemm_bt(
    const u16* __restrict__ A, const u16* __restrict__ Bt, void* __restrict__ Cptr,
    const int* __restrict__ flag, int M, int N, int Kbf, int Kf32, int ldB,
    int tapBase, long long cOff, int kChunk, int sw1, int sw2, int nSplit,
    long long zA, long long zB, long long zC) {
  __shared__ u16 lA[128 * 64];
  __shared__ u16 lB[128 * 64];
  const int f32m = flag[0];
  const int K = f32m ? Kf32 : Kbf;
  const int CB = f32m ? 768 : 256;
  int tm, tn, b = 0, kz = 0;
  if (SWZ == 1) {
    int lin = blockIdx.x, xcd = lin & 7, per = lin >> 3;
    tm = xcd * sw1 + (per % sw1);
    tn = per / sw1;
    b = blockIdx.y;
  } else if (SWZ == 2) {
    int lin = blockIdx.x, xcd = lin & 7, per = lin >> 3;
    tm = per % sw1;
    tn = xcd * sw2 + per / sw1;
    kz = blockIdx.z;
  } else {
    tm = blockIdx.x;
    tn = blockIdx.y;
    b = blockIdx.z / nSplit;
    kz = blockIdx.z % nSplit;
  }
  int k0 = 0, k1 = K;
  if (kChunk) {
    k0 = kz * kChunk;
    k1 = min(k0 + kChunk, K);
  }
  const int tid = threadIdx.x, wave = tid >> 6, lane = tid & 63;
  const int sr = lane >> 3;         // source row within 8-row issue group
  const int scw = (lane & 7) ^ sr;  // XOR-swizzled source chunk
  const int wm = (wave >> 1) * 64, wn = (wave & 1) * 64;
  const int r16 = lane & 15, q = lane >> 4;
  const u16* gA = A + (size_t)b * zA + (size_t)(tm * 128 + wave * 32 + sr) * K +
                  scw * 8;
  const u16* gB = nullptr;
  int pyI[4], pxI[4];
  size_t bOffI[4];
  if (IMC) {
#pragma unroll
    for (int i = 0; i < 4; i++) {
      int n = tn * 128 + wave * 32 + i * 8 + sr;  // global output pixel
      int bb = n >> 12, pix = n & 4095;
      pyI[i] = pix >> 6;
      pxI[i] = pix & 63;
      bOffI[i] = (size_t)bb * 4356;
    }
  } else {
    gB = Bt + (size_t)b * zB + (size_t)(tn * 128 + wave * 32 + sr) * ldB +
         scw * 8;
  }
  f32x4 acc[4][4] = {};

  for (int kt = k0; kt < k1; kt += 64) {
    int dy = 0, dx = 0, chunk = 0;
    if (IMC) {
      int t0 = kt / CB;
      chunk = kt - t0 * CB;
      int tap = tapBase + t0;
      dy = tap / 3;
      dx = tap - dy * 3;
    }
#pragma unroll
    for (int i = 0; i < 4; i++) {
      gld16(gA + (size_t)(i * 8) * K + kt, &lA[(wave * 32 + i * 8) * 64]);
      if (IMC) {
        int spix = (pyI[i] + dy) * 66 + pxI[i] + dx;
        gld16(Bt + (bOffI[i] + spix) * CB + chunk + scw * 8,
              &lB[(wave * 32 + i * 8) * 64]);
      } else {
        gld16(gB + (size_t)(i * 8) * ldB + kt, &lB[(wave * 32 + i * 8) * 64]);
      }
    }
    __syncthreads();  // drains vmcnt (gld16 complete) + prior reads done
#pragma unroll
    for (int ks = 0; ks < 64; ks += 32) {
      bf16x8 af[4], bfr[4];
#pragma unroll
      for (int f = 0; f < 4; f++) {
        int ma = wm + f * 16 + r16;
        int g = (ks >> 3) + q;
        af[f] = *(const bf16x8*)&lA[ma * 64 + ((g ^ (ma & 7)) << 3)];
        int nb = wn + f * 16 + r16;
        bfr[f] = *(const bf16x8*)&lB[nb * 64 + ((g ^ (nb & 7)) << 3)];
      }
#pragma unroll
      for (int fi = 0; fi < 4; fi++)
#pragma unroll
        for (int fj = 0; fj < 4; fj++)
          acc[fi][fj] = __builtin_amdgcn_mfma_f32_16x16x32_bf16(
              af[fi], bfr[fj], acc[fi][fj], 0, 0, 0);
    }
    __syncthreads();  // LDS reads done before next iteration's gld16
  }

  const int colB = tn * 128 + wn + r16;
  const int rowB = tm * 128 + wm + q * 4;
  float* C = (float*)Cptr + cOff + (size_t)b * zC;
  if (EPI == 0) {
#pragma unroll
    for (int fi = 0; fi < 4; fi++)
#pragma unroll
      for (int r = 0; r < 4; r++) {
        size_t ro = (size_t)(rowB + fi * 16 + r) * N;
#pragma unroll
        for (int fj = 0; fj < 4; fj++) C[ro + colB + fj * 16] = acc[fi][fj][r];
      }
  } else {
#pragma unroll
    for (int fi = 0; fi < 4; fi++)
#pragma unroll
      for (int r = 0; r < 4; r++) {
        size_t ro = (size_t)(rowB + fi * 16 + r) * N;
#pragma unroll
        for (int fj = 0; fj < 4; fj++)
          atomicAdd(&C[ro + colB + fj * 16], acc[fi][fj][r]);
      }
  }
}

// ---- 5) BN stats (biases cancel; K/V border conv-value 0, count 17424) ----
__global__ __launch_bounds__(256) void k_stats(
    const float* __restrict__ bufQ, const float* __restrict__ bufKV,
    const void* __restrict__ gq, const void* __restrict__ betaq,
    const void* __restrict__ gk, const void* __restrict__ betak,
    const void* __restrict__ gv, const void* __restrict__ betav,
    const int* __restrict__ flag, float* __restrict__ nrm) {
  int f32 = flag[0];
  int ch = blockIdx.x, t = blockIdx.y, tid = threadIdx.x;
  const float* row = (t == 0) ? bufQ + (size_t)ch * 16384
                              : bufKV + (size_t)(t == 1 ? ch : 256 + ch) * 16384;
  float s = 0.f, ss = 0.f;
  for (int i = tid; i < 16384; i += 256) {
    float v = row[i];
    s += v;
    ss += v * v;
  }
#pragma unroll
  for (int off = 32; off; off >>= 1) {
    s += __shfl_down(s, off);
    ss += __shfl_down(ss, off);
  }
  __shared__ float ls[4], lss[4];
  if ((tid & 63) == 0) {
    ls[tid >> 6] = s;
    lss[tid >> 6] = ss;
  }
  __syncthreads();
  if (tid == 0) {
    s = ls[0] + ls[1] + ls[2] + ls[3];
    ss = lss[0] + lss[1] + lss[2] + lss[3];
    float cnt = (t == 0) ? 16384.f : 17424.f;
    float mean = s / cnt;
    float var = fmaxf(ss / cnt - mean * mean, 0.f);  // NaN-proof
    const void* g = (t == 0) ? gq : (t == 1 ? gk : gv);
    const void* be = (t == 0) ? betaq : (t == 1 ? betak : betav);
    float sc = ldin(g, ch, f32) * rsqrtf(var + 1e-5f);
    nrm[(t * 256 + ch) * 2] = sc;
    nrm[(t * 256 + ch) * 2 + 1] = ldin(be, ch, f32) - mean * sc;
  }
}

// ---- 6) normalize + 3-term hi/lo split + transpose (K=768 rows) ----
__global__ __launch_bounds__(256) void k_qTs(const float* __restrict__ bufQ,
                                             const float* __restrict__ nrm,
                                             u16* __restrict__ qTs) {
  __shared__ u16 th[32][33], tl[32][33];
  int b = blockIdx.z, q0 = blockIdx.x * 32, c0 = blockIdx.y * 32;
  int tx = threadIdx.x, ty = threadIdx.y;
#pragma unroll
  for (int i = 0; i < 4; i++) {
    int c = c0 + ty + i * 8;
    float sc = nrm[c * 2], sh = nrm[c * 2 + 1];
    float v = bufQ[(size_t)c * 16384 + b * 4096 + q0 + tx] * sc + sh;
    u16 h = f2bf(v);
    th[ty + i * 8][tx] = h;
    tl[ty + i * 8][tx] = f2bf(v - bf2f(h));
  }
  __syncthreads();
#pragma unroll
  for (int i = 0; i < 4; i++) {
    size_t base = ((size_t)b * 4096 + q0 + ty + i * 8) * 768;
    u16 h = th[tx][ty + i * 8], l = tl[tx][ty + i * 8];
    qTs[base + c0 + tx] = h;  // [hi | lo | hi]
    qTs[base + 256 + c0 + tx] = l;
    qTs[base + 512 + c0 + tx] = h;
  }
}
__global__ __launch_bounds__(256) void k_kTs(const float* __restrict__ bufKV,
                                             const float* __restrict__ nrm,
                                             u16* __restrict__ kTs) {
  __shared__ u16 th[32][33], tl[32][33];
  int b = blockIdx.z, k0 = blockIdx.x * 32, c0 = blockIdx.y * 32;
  int tx = threadIdx.x, ty = threadIdx.y;
#pragma unroll
  for (int i = 0; i < 4; i++) {
    int c = c0 + ty + i * 8;
    int kt = k0 + tx;
    float v = 0.f;
    if (kt < 4356) {
      float sc = nrm[(256 + c) * 2], sh = nrm[(256 + c) * 2 + 1];
      int yy = kt / 66, xx = kt - yy * 66;
      if (yy >= 1 && yy <= 64 && xx >= 1 && xx <= 64)
        v = bufKV[(size_t)c * 16384 + b * 4096 + (yy - 1) * 64 + (xx - 1)] * sc + sh;
      else
        v = sh;  // border: conv value 0
    }
    u16 h = f2bf(v);
    th[ty + i * 8][tx] = h;
    tl[ty + i * 8][tx] = f2bf(v - bf2f(h));
  }
  __syncthreads();
#pragma unroll
  for (int i = 0; i < 4; i++) {
    size_t base = ((size_t)b * 4480 + k0 + ty + i * 8) * 768;
    u16 h = th[tx][ty + i * 8], l = tl[tx][ty + i * 8];
    kTs[base + c0 + tx] = h;  // [hi | hi | lo]
    kTs[base + 256 + c0 + tx] = h;
    kTs[base + 512 + c0 + tx] = l;
  }
}

// ---- 7) normalized V, [b][c][4480], pads zero ----
__global__ __launch_bounds__(256) void k_vP(const float* __restrict__ bufKV,
                                            const float* __restrict__ nrm,
                                            u16* __restrict__ vP) {
  int b = blockIdx.z, ch = blockIdx.y;
  int kt = blockIdx.x * 256 + threadIdx.x;
  if (kt >= 4480) return;
  float v = 0.f;
  if (kt < 4356) {
    float sc = nrm[(512 + ch) * 2], sh = nrm[(512 + ch) * 2 + 1];
    int yy = kt / 66, xx = kt - yy * 66;
    if (yy >= 1 && yy <= 64 && xx >= 1 && xx <= 64)
      v = bufKV[(size_t)(256 + ch) * 16384 + b * 4096 + (yy - 1) * 64 + (xx - 1)] * sc + sh;
    else
      v = sh;
  }
  vP[((size_t)b * 256 + ch) * 4480 + kt] = f2bf(v);
}

// ---- 8) softmax over kt: bf16 p written IN PLACE over St (ld 8960 u16) ----
// Row index = blockIdx.x (contiguous across batches in batched mode).
__global__ __launch_bounds__(256) void k_softmax(float* __restrict__ St,
                                                 float* __restrict__ sumP) {
  __shared__ float row[4480];
  __shared__ float red[4], red2[4];
  int qt = blockIdx.x, tid = threadIdx.x;
  float* srow = St + (size_t)qt * 4480;
  float m = -3.0e38f;
  for (int kt = tid; kt < 4480; kt += 256) {
    float v = srow[kt];
    row[kt] = v;
    if (kt < 4356) m = fmaxf(m, v);
  }
#pragma unroll
  for (int off = 32; off; off >>= 1) m = fmaxf(m, __shfl_down(m, off));
  if ((tid & 63) == 0) red[tid >> 6] = m;
  __syncthreads();  // all srow reads complete before in-place writes
  m = fmaxf(fmaxf(red[0], red[1]), fmaxf(red[2], red[3]));
  u16* prow = (u16*)srow;
  float psum = 0.f;
  for (int kt = tid; kt < 4480; kt += 256) {
    u16 h = 0;
    if (kt < 4356) {
      float p = __expf(fminf(row[kt] - m, 0.f));  // in (0,1], NaN-proof
      h = f2bf(p);
      psum += bf2f(h);
    }
    prow[kt] = h;
  }
#pragma unroll
  for (int off = 32; off; off >>= 1) psum += __shfl_down(psum, off);
  if ((tid & 63) == 0) red2[tid >> 6] = psum;
  __syncthreads();
  if (tid == 0) sumP[qt] = red2[0] + red2[1] + red2[2] + red2[3];  // >= 1
}

// ---- 9) split-K support ----
__global__ __launch_bounds__(256) void k_zeroacc(float* __restrict__ accF) {
  accF[blockIdx.x * 256 + threadIdx.x] = 0.f;
}
__global__ __launch_bounds__(256) void k_final(const float* __restrict__ accF,
                                               const float* __restrict__ sumP,
                                               const int* __restrict__ flag,
                                               void* __restrict__ out,
                                               long long cOff) {
  int idx = blockIdx.x * 256 + threadIdx.x;  // [b][c][qt] flat
  int sidx = ((idx >> 20) << 12) | (idx & 4095);  // b*4096 + qt
  float v = accF[idx] / sumP[sidx];  // sumP >= 1
  v = (v == v) ? v : 0.f;            // NaN scrub: keep failures diagnostic
  if (flag[0])
    ((float*)out)[cOff + idx] = v;
  else
    ((u16*)out)[cOff + idx] = f2bf(v);
}

// ---------------------------------------------------------------------------
extern "C" void kernel_launch(void* const* d_in, const int* in_sizes, int n_in,
                              void* d_out, int out_size, void* d_ws, size_t ws_size,
                              hipStream_t stream) {
  const void* x = d_in[0];
  const void* Wq = d_in[1];
  const void* gq = d_in[3];
  const void* betaq = d_in[4];
  const void* Wk = d_in[5];
  const void* gk = d_in[7];
  const void* betak = d_in[8];
  const void* Wv = d_in[9];
  const void* gv = d_in[11];
  const void* betav = d_in[12];

  const bool batched = ws_size >= 372316416ull;
  char* ws = (char*)d_ws;
  int* flag = (int*)ws;                    // 256 B
  // Region A (conv phase; dead before St is written):
  u16* xbTp = (u16*)(ws + 256);            // 26,763,264
  u16* WqB = (u16*)(ws + 26763520);        //  3,538,944
  u16* WkvB = (u16*)(ws + 30302464);       //    786,432
  float* bufQ = (float*)(ws + 31088896);   // 16,777,216
  float* bufKV = (float*)(ws + 47866112);  // 33,554,432 -> A ends 81,420,544
  // St overlays region A. Loop: 1 batch (73.4 MB). Batched: 4 (293.6 MB).
  float* St = (float*)(ws + 256);
  // Region B (persistent): after A (loop) or after St4 (batched).
  size_t rb = batched ? 293601536ull : 81420544ull;
  u16* qTs = (u16*)(ws + rb);                   // 25,165,824 (4*4096*768*2)
  u16* kTs = (u16*)(ws + rb + 25165824);        // 27,525,120 (4*4480*768*2)
  u16* vP = (u16*)(ws + rb + 52690944);         //  9,175,040
  float* nrm = (float*)(ws + rb + 61865984);    //      6,144
  float* sumP4 = (float*)(ws + rb + 61872128);  //     65,536 -> rb+61,937,664
  // accF: loop = 4 MB in region A tail; batched = 16.8 MB after region B
  // (batched total = 293,601,536 + 61,937,664 + 16,777,216 = 372,316,416).
  float* accF = batched ? (float*)(ws + rb + 61937664) : (float*)(ws + 73400576);

  dim3 b32x8(32, 8);
  k_detect<<<1, 256, 0, stream>>>((const unsigned*)Wq, flag);
  k_txp<<<dim3(137, 8, 4), b32x8, 0, stream>>>(x, flag, xbTp);
  k_wq<<<6912, 256, 0, stream>>>(Wq, flag, WqB);
  k_wkv<<<1536, 256, 0, stream>>>(Wk, Wv, flag, WkvB);
  // conv3x3: split-K x3 (chunk 2304) into zeroed bufQ; 768 blocks.
  k_zeroacc<<<16384, 256, 0, stream>>>(bufQ);
  gemm_bt<true, 1, 2><<<dim3(256, 1, 3), 256, 0, stream>>>(
      WqB, xbTp, bufQ, flag, 256, 16384, 2304, 6912, 0, 0, 0, 2304, 2, 16, 1,
      0, 0, 0);
  // conv1x1: grid 512 = 8 XCD x (4 tm x 16 tn-band)
  gemm_bt<true, 0, 2><<<512, 256, 0, stream>>>(
      WkvB, xbTp, bufKV, flag, 512, 16384, 256, 768, 0, 4, 0, 0, 4, 16, 1,
      0, 0, 0);
  k_stats<<<dim3(256, 3), 256, 0, stream>>>(bufQ, bufKV, gq, betaq, gk, betak,
                                            gv, betav, flag, nrm);
  k_qTs<<<dim3(128, 8, 4), b32x8, 0, stream>>>(bufQ, nrm, qTs);
  k_kTs<<<dim3(140, 8, 4), b32x8, 0, stream>>>(bufKV, nrm, kTs);
  k_vP<<<dim3(18, 256, 4), 256, 0, stream>>>(bufKV, nrm, vP);

  if (batched) {
    // scores: all 4 batches, grid (1120,4); K=768 3-term split GEMM
    gemm_bt<false, 0, 1><<<dim3(1120, 4), 256, 0, stream>>>(
        qTs, kTs, St, flag, 4096, 4480, 768, 768, 768, 0, 0, 0, 4, 0, 1,
        4096LL * 768, 4480LL * 768, 4096LL * 4480);
    k_softmax<<<16384, 256, 0, stream>>>(St, sumP4);
    k_zeroacc<<<16384, 256, 0, stream>>>(accF);
    // PV: all 4 batches, split-K x5 (chunk 896): grid (2,32,20)
    gemm_bt<false, 1, 0><<<dim3(2, 32, 20), 256, 0, stream>>>(
        vP, (const u16*)St, accF, flag, 256, 4096, 4480, 4480, 8960, 0, 0,
        896, 0, 0, 5, 256LL * 4480, 4096LL * 8960, 256LL * 4096);
    k_final<<<16384, 256, 0, stream>>>(accF, sumP4, flag, d_out, 0);
  } else {
    for (int b = 0; b < 4; b++) {
      gemm_bt<false, 0, 1><<<dim3(1120, 1), 256, 0, stream>>>(
          qTs + (size_t)b * 4096 * 768, kTs + (size_t)b * 4480 * 768, St, flag,
          4096, 4480, 768, 768, 768, 0, 0, 0, 4, 0, 1, 0, 0, 0);
      k_softmax<<<4096, 256, 0, stream>>>(St, sumP4 + b * 4096);
      k_zeroacc<<<4096, 256, 0, stream>>>(accF);
      gemm_bt<false, 1, 0><<<dim3(2, 32, 7), 256, 0, stream>>>(
          vP + (size_t)b * 256 * 4480, (const u16*)St, accF, flag,
          256, 4096, 4480, 4480, 8960, 0, 0, 640, 0, 0, 7, 0, 0, 0);
      k_final<<<4096, 256, 0, stream>>>(accF, sumP4 + (size_t)b * 4096, flag,
                                        d_out, (long long)b * 1048576);
    }
  }
}

// Round 10
// 622.779 us; speedup vs baseline: 1.2498x; 1.1742x over previous
//
#include <hip/hip_runtime.h>

// ---------------------------------------------------------------------------
// ChannelAttentionLayer on MI355X (gfx950). Input dtype (fp32 vs bf16) is
// DETECTED ON DEVICE (k_detect); core pipeline is FP16 MFMA + fp32 accumulate.
// R9->R10: switch all GEMMs from bf16+hi/lo-splits to single fp16 GEMMs
// (mfma_f32_16x16x32_f16, same rate as bf16; 11-bit mantissa makes splits
// unnecessary: logit err sigma ~0.006 vs bf16-2-term's 0.06 that failed R8).
// Scores K 768->256, conv3x3 K 6912->2304, P/V fp16 (cuts PV rounding 8x).
// GEMM structure = R6 single-buffered 3-blocks/CU (best measured). Batched
// attention phases engage if ws_size >= 337,189,120; else per-batch loop.
// ---------------------------------------------------------------------------

typedef unsigned short u16;
typedef _Float16 f16x8 __attribute__((ext_vector_type(8)));
typedef __attribute__((ext_vector_type(4))) float f32x4;

__device__ __forceinline__ u16 f2h(float f) {
  _Float16 h = (_Float16)f;
  return *(const u16*)&h;
}
__device__ __forceinline__ float bf2f(u16 h) {
  return __uint_as_float(((unsigned)h) << 16);
}
__device__ __forceinline__ float ldin(const void* p, size_t i, int f32) {
  return f32 ? ((const float*)p)[i] : bf2f(((const u16*)p)[i]);
}
__device__ __forceinline__ u16 f2bf(float f) {
  unsigned u = __float_as_uint(f);
  u += 0x7fffu + ((u >> 16) & 1u);
  return (u16)(u >> 16);
}
__device__ __forceinline__ void gld16(const void* g, void* l) {
  __builtin_amdgcn_global_load_lds(
      (const __attribute__((address_space(1))) unsigned int*)g,
      (__attribute__((address_space(3))) unsigned int*)l, 16, 0, 0);
}

// ---- 1) dtype detection on Wq (low 16 bits of each u32 word) ----
__global__ __launch_bounds__(256) void k_detect(const unsigned* __restrict__ w,
                                                int* __restrict__ flag) {
  __shared__ int red[4];
  int tid = threadIdx.x, cnt = 0;
  for (int i = tid; i < 65536; i += 256) {
    unsigned e = (w[i] >> 7) & 0xFFu;
    cnt += (e >= 118u && e <= 127u) ? 1 : 0;
  }
#pragma unroll
  for (int off = 32; off; off >>= 1) cnt += __shfl_down(cnt, off);
  if ((tid & 63) == 0) red[tid >> 6] = cnt;
  __syncthreads();
  if (tid == 0)
    flag[0] = (red[0] + red[1] + red[2] + red[3] < 20000) ? 1 : 0;  // 1 = fp32
}

// ---- 2) pad+transpose x -> fp16 [b][66*66 pix][256c], zero border ----
__global__ __launch_bounds__(256) void k_txp(const void* __restrict__ x,
                                             const int* __restrict__ flag,
                                             u16* __restrict__ xbTp) {
  __shared__ float tile[32][33];
  int f32 = flag[0];
  int b = blockIdx.z, p0 = blockIdx.x * 32, c0 = blockIdx.y * 32;
  int tx = threadIdx.x, ty = threadIdx.y;
#pragma unroll
  for (int i = 0; i < 4; i++) {
    int c = c0 + ty + i * 8, pp = p0 + tx;
    float v = 0.f;
    if (pp < 4356) {
      int yy = pp / 66, xx = pp - yy * 66;
      if (yy >= 1 && yy <= 64 && xx >= 1 && xx <= 64)
        v = ldin(x, ((size_t)b * 256 + c) * 4096 + (yy - 1) * 64 + (xx - 1), f32);
    }
    tile[ty + i * 8][tx] = v;
  }
  __syncthreads();
#pragma unroll
  for (int i = 0; i < 4; i++) {
    int pp = p0 + ty + i * 8;
    if (pp >= 4356) continue;
    xbTp[((size_t)b * 4356 + pp) * 256 + c0 + tx] = f2h(tile[tx][ty + i * 8]);
  }
}

// ---- 3) weight reorders (fp16) ----
__global__ __launch_bounds__(256) void k_wq(const void* __restrict__ Wq,
                                            const int* __restrict__ flag,
                                            u16* __restrict__ WqB) {
  int idx = blockIdx.x * 256 + threadIdx.x;  // 256*2304
  int oc = idx / 2304, rem = idx - oc * 2304;
  int tap = rem >> 8, c = rem & 255;
  WqB[idx] = f2h(ldin(Wq, oc * 2304 + c * 9 + tap, flag[0]));
}
__global__ __launch_bounds__(256) void k_wkv(const void* __restrict__ Wk,
                                             const void* __restrict__ Wv,
                                             const int* __restrict__ flag,
                                             u16* __restrict__ WkvB) {
  int idx = blockIdx.x * 256 + threadIdx.x;  // 512*256
  int m = idx >> 8, c = idx & 255;
  float w = (m < 256) ? ldin(Wk, m * 256 + c, flag[0])
                      : ldin(Wv, (m - 256) * 256 + c, flag[0]);
  WkvB[idx] = f2h(w);
}

// ---- GEMM (fp16): C[M][N] = A[M][K] . Bt[N][K]^T  (R6 1-buf structure) ----
// Staging: global_load_lds width 16, XOR-swizzled packed LDS
// (LDS(r,c) = G(r, c^(r&7)); frag reads 2-way = free).
// IMC: B rows are implicit-im2col reads of xbTp (tap = tapBase + kt/256).
// EPI 0: fp32 store at C+cOff+b*zC.  EPI 1: fp32 atomicAdd (split-K partials).
// SWZ 1: tm banded per XCD (sw1 = tm tiles/XCD), batch b = blockIdx.y.
// SWZ 2: tn banded per XCD (sw1 = tm tiles, sw2 = tn tiles/XCD), kz = bz.
// SWZ 0: (bx,by) tiles; blockIdx.z = b*nSplit + kz (split-K, batched).
template <bool IMC, int EPI, int SWZ>
__global__ __launch_bounds__(256, 3) void gemm_bt(
    const u16* __restrict__ A, const u16* __restrict__ Bt, void* __restrict__ Cptr,
    int M, int N, int K, int ldB, int tapBase, long long cOff, int kChunk,
    int sw1, int sw2, int nSplit, long long zA, long long zB, long long zC) {
  __shared__ u16 lA[128 * 64];
  __shared__ u16 lB[128 * 64];
  int tm, tn, b = 0, kz = 0;
  if (SWZ == 1) {
    int lin = blockIdx.x, xcd = lin & 7, per = lin >> 3;
    tm = xcd * sw1 + (per % sw1);
    tn = per / sw1;
    b = blockIdx.y;
  } else if (SWZ == 2) {
    int lin = blockIdx.x, xcd = lin & 7, per = lin >> 3;
    tm = per % sw1;
    tn = xcd * sw2 + per / sw1;
    kz = blockIdx.z;
  } else {
    tm = blockIdx.x;
    tn = blockIdx.y;
    b = blockIdx.z / nSplit;
    kz = blockIdx.z % nSplit;
  }
  int k0 = 0, k1 = K;
  if (kChunk) {
    k0 = kz * kChunk;
    k1 = min(k0 + kChunk, K);
  }
  const int tid = threadIdx.x, wave = tid >> 6, lane = tid & 63;
  const int sr = lane >> 3;         // source row within 8-row issue group
  const int scw = (lane & 7) ^ sr;  // XOR-swizzled source chunk
  const int wm = (wave >> 1) * 64, wn = (wave & 1) * 64;
  const int r16 = lane & 15, q = lane >> 4;
  const u16* gA = A + (size_t)b * zA + (size_t)(tm * 128 + wave * 32 + sr) * K +
                  scw * 8;
  const u16* gB = nullptr;
  int pyI[4], pxI[4];
  size_t bOffI[4];
  if (IMC) {
#pragma unroll
    for (int i = 0; i < 4; i++) {
      int n = tn * 128 + wave * 32 + i * 8 + sr;  // global output pixel
      int bb = n >> 12, pix = n & 4095;
      pyI[i] = pix >> 6;
      pxI[i] = pix & 63;
      bOffI[i] = (size_t)bb * 4356;
    }
  } else {
    gB = Bt + (size_t)b * zB + (size_t)(tn * 128 + wave * 32 + sr) * ldB +
         scw * 8;
  }
  f32x4 acc[4][4] = {};

  for (int kt = k0; kt < k1; kt += 64) {
    int dy = 0, dx = 0, chunk = 0;
    if (IMC) {
      int tap = tapBase + (kt >> 8);
      chunk = kt & 255;
      dy = tap / 3;
      dx = tap - dy * 3;
    }
#pragma unroll
    for (int i = 0; i < 4; i++) {
      gld16(gA + (size_t)(i * 8) * K + kt, &lA[(wave * 32 + i * 8) * 64]);
      if (IMC) {
        int spix = (pyI[i] + dy) * 66 + pxI[i] + dx;
        gld16(Bt + (bOffI[i] + spix) * 256 + chunk + scw * 8,
              &lB[(wave * 32 + i * 8) * 64]);
      } else {
        gld16(gB + (size_t)(i * 8) * ldB + kt, &lB[(wave * 32 + i * 8) * 64]);
      }
    }
    __syncthreads();  // drains vmcnt (gld16 complete) + prior reads done
#pragma unroll
    for (int ks = 0; ks < 64; ks += 32) {
      f16x8 af[4], bfr[4];
#pragma unroll
      for (int f = 0; f < 4; f++) {
        int ma = wm + f * 16 + r16;
        int g = (ks >> 3) + q;
        af[f] = *(const f16x8*)&lA[ma * 64 + ((g ^ (ma & 7)) << 3)];
        int nb = wn + f * 16 + r16;
        bfr[f] = *(const f16x8*)&lB[nb * 64 + ((g ^ (nb & 7)) << 3)];
      }
#pragma unroll
      for (int fi = 0; fi < 4; fi++)
#pragma unroll
        for (int fj = 0; fj < 4; fj++)
          acc[fi][fj] = __builtin_amdgcn_mfma_f32_16x16x32_f16(
              af[fi], bfr[fj], acc[fi][fj], 0, 0, 0);
    }
    __syncthreads();  // LDS reads done before next iteration's gld16
  }

  const int colB = tn * 128 + wn + r16;
  const int rowB = tm * 128 + wm + q * 4;
  float* C = (float*)Cptr + cOff + (size_t)b * zC;
  if (EPI == 0) {
#pragma unroll
    for (int fi = 0; fi < 4; fi++)
#pragma unroll
      for (int r = 0; r < 4; r++) {
        size_t ro = (size_t)(rowB + fi * 16 + r) * N;
#pragma unroll
        for (int fj = 0; fj < 4; fj++) C[ro + colB + fj * 16] = acc[fi][fj][r];
      }
  } else {
#pragma unroll
    for (int fi = 0; fi < 4; fi++)
#pragma unroll
      for (int r = 0; r < 4; r++) {
        size_t ro = (size_t)(rowB + fi * 16 + r) * N;
#pragma unroll
        for (int fj = 0; fj < 4; fj++)
          atomicAdd(&C[ro + colB + fj * 16], acc[fi][fj][r]);
      }
  }
}

// ---- 5) BN stats (biases cancel; K/V border conv-value 0, count 17424) ----
__global__ __launch_bounds__(256) void k_stats(
    const float* __restrict__ bufQ, const float* __restrict__ bufKV,
    const void* __restrict__ gq, const void* __restrict__ betaq,
    const void* __restrict__ gk, const void* __restrict__ betak,
    const void* __restrict__ gv, const void* __restrict__ betav,
    const int* __restrict__ flag, float* __restrict__ nrm) {
  int f32 = flag[0];
  int ch = blockIdx.x, t = blockIdx.y, tid = threadIdx.x;
  const float* row = (t == 0) ? bufQ + (size_t)ch * 16384
                              : bufKV + (size_t)(t == 1 ? ch : 256 + ch) * 16384;
  float s = 0.f, ss = 0.f;
  for (int i = tid; i < 16384; i += 256) {
    float v = row[i];
    s += v;
    ss += v * v;
  }
#pragma unroll
  for (int off = 32; off; off >>= 1) {
    s += __shfl_down(s, off);
    ss += __shfl_down(ss, off);
  }
  __shared__ float ls[4], lss[4];
  if ((tid & 63) == 0) {
    ls[tid >> 6] = s;
    lss[tid >> 6] = ss;
  }
  __syncthreads();
  if (tid == 0) {
    s = ls[0] + ls[1] + ls[2] + ls[3];
    ss = lss[0] + lss[1] + lss[2] + lss[3];
    float cnt = (t == 0) ? 16384.f : 17424.f;
    float mean = s / cnt;
    float var = fmaxf(ss / cnt - mean * mean, 0.f);  // NaN-proof
    const void* g = (t == 0) ? gq : (t == 1 ? gk : gv);
    const void* be = (t == 0) ? betaq : (t == 1 ? betak : betav);
    float sc = ldin(g, ch, f32) * rsqrtf(var + 1e-5f);
    nrm[(t * 256 + ch) * 2] = sc;
    nrm[(t * 256 + ch) * 2 + 1] = ldin(be, ch, f32) - mean * sc;
  }
}

// ---- 6) normalize + transpose to fp16 (K=256 rows) ----
__global__ __launch_bounds__(256) void k_qTs(const float* __restrict__ bufQ,
                                             const float* __restrict__ nrm,
                                             u16* __restrict__ qTs) {
  __shared__ u16 th[32][33];
  int b = blockIdx.z, q0 = blockIdx.x * 32, c0 = blockIdx.y * 32;
  int tx = threadIdx.x, ty = threadIdx.y;
#pragma unroll
  for (int i = 0; i < 4; i++) {
    int c = c0 + ty + i * 8;
    float sc = nrm[c * 2], sh = nrm[c * 2 + 1];
    th[ty + i * 8][tx] =
        f2h(bufQ[(size_t)c * 16384 + b * 4096 + q0 + tx] * sc + sh);
  }
  __syncthreads();
#pragma unroll
  for (int i = 0; i < 4; i++)
    qTs[((size_t)b * 4096 + q0 + ty + i * 8) * 256 + c0 + tx] =
        th[tx][ty + i * 8];
}
__global__ __launch_bounds__(256) void k_kTs(const float* __restrict__ bufKV,
                                             const float* __restrict__ nrm,
                                             u16* __restrict__ kTs) {
  __shared__ u16 th[32][33];
  int b = blockIdx.z, k0 = blockIdx.x * 32, c0 = blockIdx.y * 32;
  int tx = threadIdx.x, ty = threadIdx.y;
#pragma unroll
  for (int i = 0; i < 4; i++) {
    int c = c0 + ty + i * 8;
    int kt = k0 + tx;
    float v = 0.f;
    if (kt < 4356) {
      float sc = nrm[(256 + c) * 2], sh = nrm[(256 + c) * 2 + 1];
      int yy = kt / 66, xx = kt - yy * 66;
      if (yy >= 1 && yy <= 64 && xx >= 1 && xx <= 64)
        v = bufKV[(size_t)c * 16384 + b * 4096 + (yy - 1) * 64 + (xx - 1)] * sc + sh;
      else
        v = sh;  // border: conv value 0
    }
    th[ty + i * 8][tx] = f2h(v);
  }
  __syncthreads();
#pragma unroll
  for (int i = 0; i < 4; i++)
    kTs[((size_t)b * 4480 + k0 + ty + i * 8) * 256 + c0 + tx] =
        th[tx][ty + i * 8];
}

// ---- 7) normalized V fp16, [b][c][4480], pads zero ----
__global__ __launch_bounds__(256) void k_vP(const float* __restrict__ bufKV,
                                            const float* __restrict__ nrm,
                                            u16* __restrict__ vP) {
  int b = blockIdx.z, ch = blockIdx.y;
  int kt = blockIdx.x * 256 + threadIdx.x;
  if (kt >= 4480) return;
  float v = 0.f;
  if (kt < 4356) {
    float sc = nrm[(512 + ch) * 2], sh = nrm[(512 + ch) * 2 + 1];
    int yy = kt / 66, xx = kt - yy * 66;
    if (yy >= 1 && yy <= 64 && xx >= 1 && xx <= 64)
      v = bufKV[(size_t)(256 + ch) * 16384 + b * 4096 + (yy - 1) * 64 + (xx - 1)] * sc + sh;
    else
      v = sh;
  }
  vP[((size_t)b * 256 + ch) * 4480 + kt] = f2h(v);
}

// ---- 8) softmax over kt: fp16 p written IN PLACE over St (ld 8960 u16) ----
__global__ __launch_bounds__(256) void k_softmax(float* __restrict__ St,
                                                 float* __restrict__ sumP) {
  __shared__ float row[4480];
  __shared__ float red[4], red2[4];
  int qt = blockIdx.x, tid = threadIdx.x;
  float* srow = St + (size_t)qt * 4480;
  float m = -3.0e38f;
  for (int kt = tid; kt < 4480; kt += 256) {
    float v = srow[kt];
    row[kt] = v;
    if (kt < 4356) m = fmaxf(m, v);
  }
#pragma unroll
  for (int off = 32; off; off >>= 1) m = fmaxf(m, __shfl_down(m, off));
  if ((tid & 63) == 0) red[tid >> 6] = m;
  __syncthreads();  // all srow reads complete before in-place writes
  m = fmaxf(fmaxf(red[0], red[1]), fmaxf(red[2], red[3]));
  u16* prow = (u16*)srow;
  float psum = 0.f;
  for (int kt = tid; kt < 4480; kt += 256) {
    u16 hb = 0;
    if (kt < 4356) {
      float p = __expf(fminf(row[kt] - m, 0.f));  // in (0,1], NaN-proof
      _Float16 h = (_Float16)p;
      hb = *(const u16*)&h;
      psum += (float)h;  // sum the rounded values for consistency
    }
    prow[kt] = hb;
  }
#pragma unroll
  for (int off = 32; off; off >>= 1) psum += __shfl_down(psum, off);
  if ((tid & 63) == 0) red2[tid >> 6] = psum;
  __syncthreads();
  if (tid == 0) sumP[qt] = red2[0] + red2[1] + red2[2] + red2[3];  // >= 1
}

// ---- 9) split-K support ----
__global__ __launch_bounds__(256) void k_zeroacc(float* __restrict__ accF) {
  accF[blockIdx.x * 256 + threadIdx.x] = 0.f;
}
__global__ __launch_bounds__(256) void k_final(const float* __restrict__ accF,
                                               const float* __restrict__ sumP,
                                               const int* __restrict__ flag,
                                               void* __restrict__ out,
                                               long long cOff) {
  int idx = blockIdx.x * 256 + threadIdx.x;       // [b][c][qt] flat
  int sidx = ((idx >> 20) << 12) | (idx & 4095);  // b*4096 + qt
  float v = accF[idx] / sumP[sidx];               // sumP >= 1
  v = (v == v) ? v : 0.f;  // NaN scrub: keep failures diagnostic
  if (flag[0])
    ((float*)out)[cOff + idx] = v;
  else
    ((u16*)out)[cOff + idx] = f2bf(v);
}

// ---------------------------------------------------------------------------
extern "C" void kernel_launch(void* const* d_in, const int* in_sizes, int n_in,
                              void* d_out, int out_size, void* d_ws, size_t ws_size,
                              hipStream_t stream) {
  const void* x = d_in[0];
  const void* Wq = d_in[1];
  const void* gq = d_in[3];
  const void* betaq = d_in[4];
  const void* Wk = d_in[5];
  const void* gk = d_in[7];
  const void* betak = d_in[8];
  const void* Wv = d_in[9];
  const void* gv = d_in[11];
  const void* betav = d_in[12];

  const bool batched = ws_size >= 337189120ull;
  char* ws = (char*)d_ws;
  int* flag = (int*)ws;                    // 256 B
  // Region A (conv phase; overlaid by St before attention):
  u16* xbTp = (u16*)(ws + 256);            //  8,921,088
  u16* WqB = (u16*)(ws + 8921344);         //  1,179,648
  u16* WkvB = (u16*)(ws + 10100992);       //    262,144
  float* bufQ = (float*)(ws + 10363136);   // 16,777,216
  float* bufKV = (float*)(ws + 27140352);  // 33,554,432 -> A ends 60,694,784
  // St overlays region A. Loop: 1 batch (73.4 MB). Batched: 4 (293.6 MB).
  float* St = (float*)(ws + 256);
  size_t rb = batched ? 293601536ull : 73400576ull;
  u16* qTs = (u16*)(ws + rb);                   //  8,388,608 (4*4096*256*2)
  u16* kTs = (u16*)(ws + rb + 8388608);         //  9,175,040 (4*4480*256*2)
  u16* vP = (u16*)(ws + rb + 17563648);         //  9,175,040
  float* nrm = (float*)(ws + rb + 26738688);    //      6,144
  float* sumP4 = (float*)(ws + rb + 26744832);  //     65,536
  float* accF = (float*)(ws + rb + 26810368);   // 4 MB loop / 16.8 MB batched
  // totals: loop 104,405,248 B; batched 337,189,120 B.

  dim3 b32x8(32, 8);
  k_detect<<<1, 256, 0, stream>>>((const unsigned*)Wq, flag);
  k_txp<<<dim3(137, 8, 4), b32x8, 0, stream>>>(x, flag, xbTp);
  k_wq<<<2304, 256, 0, stream>>>(Wq, flag, WqB);
  k_wkv<<<512, 256, 0, stream>>>(Wk, Wv, flag, WkvB);
  // conv3x3: K=2304 split-K x3 (chunk 768) into zeroed bufQ; 768 blocks.
  k_zeroacc<<<16384, 256, 0, stream>>>(bufQ);
  gemm_bt<true, 1, 2><<<dim3(256, 1, 3), 256, 0, stream>>>(
      WqB, xbTp, bufQ, 256, 16384, 2304, 0, 0, 0, 768, 2, 16, 1, 0, 0, 0);
  // conv1x1: K=256; grid 512 = 8 XCD x (4 tm x 16 tn-band)
  gemm_bt<true, 0, 2><<<512, 256, 0, stream>>>(
      WkvB, xbTp, bufKV, 512, 16384, 256, 0, 4, 0, 0, 4, 16, 1, 0, 0, 0);
  k_stats<<<dim3(256, 3), 256, 0, stream>>>(bufQ, bufKV, gq, betaq, gk, betak,
                                            gv, betav, flag, nrm);
  k_qTs<<<dim3(128, 8, 4), b32x8, 0, stream>>>(bufQ, nrm, qTs);
  k_kTs<<<dim3(140, 8, 4), b32x8, 0, stream>>>(bufKV, nrm, kTs);
  k_vP<<<dim3(18, 256, 4), 256, 0, stream>>>(bufKV, nrm, vP);

  if (batched) {
    // scores: all 4 batches, grid (1120,4); single fp16 GEMM K=256
    gemm_bt<false, 0, 1><<<dim3(1120, 4), 256, 0, stream>>>(
        qTs, kTs, St, 4096, 4480, 256, 256, 0, 0, 0, 4, 0, 1, 4096LL * 256,
        4480LL * 256, 4096LL * 4480);
    k_softmax<<<16384, 256, 0, stream>>>(St, sumP4);
    k_zeroacc<<<16384, 256, 0, stream>>>(accF);
    // PV: all 4 batches, split-K x5 (chunk 896): grid (2,32,20)
    gemm_bt<false, 1, 0><<<dim3(2, 32, 20), 256, 0, stream>>>(
        vP, (const u16*)St, accF, 256, 4096, 4480, 8960, 0, 0, 896, 0, 0, 5,
        256LL * 4480, 4096LL * 8960, 256LL * 4096);
    k_final<<<16384, 256, 0, stream>>>(accF, sumP4, flag, d_out, 0);
  } else {
    for (int b = 0; b < 4; b++) {
      gemm_bt<false, 0, 1><<<dim3(1120, 1), 256, 0, stream>>>(
          qTs + (size_t)b * 4096 * 256, kTs + (size_t)b * 4480 * 256, St, 4096,
          4480, 256, 256, 0, 0, 0, 4, 0, 1, 0, 0, 0);
      k_softmax<<<4096, 256, 0, stream>>>(St, sumP4 + b * 4096);
      k_zeroacc<<<4096, 256, 0, stream>>>(accF);
      gemm_bt<false, 1, 0><<<dim3(2, 32, 7), 256, 0, stream>>>(
          vP + (size_t)b * 256 * 4480, (const u16*)St, accF, 256, 4096, 4480,
          8960, 0, 0, 640, 0, 0, 7, 0, 0, 0);
      k_final<<<4096, 256, 0, stream>>>(accF, sumP4 + (size_t)b * 4096, flag,
                                        d_out, (long long)b * 1048576);
    }
  }
}

// Round 11
// 510.468 us; speedup vs baseline: 1.5248x; 1.2200x over previous
//
#include <hip/hip_runtime.h>

// ---------------------------------------------------------------------------
// ChannelAttentionLayer on MI355X (gfx950). Input dtype (fp32 vs bf16) is
// DETECTED ON DEVICE (k_detect); core pipeline is FP16 MFMA + fp32 accumulate.
// R10->R11: (a) k_detect was 61 us (one block, 256 serialized loads/thread)
// -> now 2048 samples, 8 independent loads/thread, ~5 us. (b) attention runs
// in TWO 2-batch mega-phases when ws_size >= 181,999,872 B (St x2 = 146.8 MB
// overlays conv buffers): scores (1120,2), softmax 8192, PV (2,32,10), one
// zero/final per phase — halves tails and dispatch bubbles vs 4-batch loop.
// Loop fallback (104 MB) = R10 exactly. GEMM = R6 single-buffered 3-blk/CU.
// ---------------------------------------------------------------------------

typedef unsigned short u16;
typedef _Float16 f16x8 __attribute__((ext_vector_type(8)));
typedef __attribute__((ext_vector_type(4))) float f32x4;

__device__ __forceinline__ u16 f2h(float f) {
  _Float16 h = (_Float16)f;
  return *(const u16*)&h;
}
__device__ __forceinline__ float bf2f(u16 h) {
  return __uint_as_float(((unsigned)h) << 16);
}
__device__ __forceinline__ float ldin(const void* p, size_t i, int f32) {
  return f32 ? ((const float*)p)[i] : bf2f(((const u16*)p)[i]);
}
__device__ __forceinline__ u16 f2bf(float f) {
  unsigned u = __float_as_uint(f);
  u += 0x7fffu + ((u >> 16) & 1u);
  return (u16)(u >> 16);
}
__device__ __forceinline__ void gld16(const void* g, void* l) {
  __builtin_amdgcn_global_load_lds(
      (const __attribute__((address_space(1))) unsigned int*)g,
      (__attribute__((address_space(3))) unsigned int*)l, 16, 0, 0);
}

// ---- 1) dtype detection on Wq: 2048 sampled words, 8 independent loads ----
// fp32 data: low16 random mantissa -> ~4% (~80) in bf16-exp band [118,127].
// bf16 data: low16 is a real weight -> ~92% (~1880) in band. Threshold 625.
__global__ __launch_bounds__(256) void k_detect(const unsigned* __restrict__ w,
                                                int* __restrict__ flag) {
  __shared__ int red[4];
  int tid = threadIdx.x, cnt = 0;
#pragma unroll
  for (int j = 0; j < 8; j++) {
    unsigned e = (w[tid + j * 8192] >> 7) & 0xFFu;
    cnt += (e >= 118u && e <= 127u) ? 1 : 0;
  }
#pragma unroll
  for (int off = 32; off; off >>= 1) cnt += __shfl_down(cnt, off);
  if ((tid & 63) == 0) red[tid >> 6] = cnt;
  __syncthreads();
  if (tid == 0)
    flag[0] = (red[0] + red[1] + red[2] + red[3] < 625) ? 1 : 0;  // 1 = fp32
}

// ---- 2) pad+transpose x -> fp16 [b][66*66 pix][256c], zero border ----
__global__ __launch_bounds__(256) void k_txp(const void* __restrict__ x,
                                             const int* __restrict__ flag,
                                             u16* __restrict__ xbTp) {
  __shared__ float tile[32][33];
  int f32 = flag[0];
  int b = blockIdx.z, p0 = blockIdx.x * 32, c0 = blockIdx.y * 32;
  int tx = threadIdx.x, ty = threadIdx.y;
#pragma unroll
  for (int i = 0; i < 4; i++) {
    int c = c0 + ty + i * 8, pp = p0 + tx;
    float v = 0.f;
    if (pp < 4356) {
      int yy = pp / 66, xx = pp - yy * 66;
      if (yy >= 1 && yy <= 64 && xx >= 1 && xx <= 64)
        v = ldin(x, ((size_t)b * 256 + c) * 4096 + (yy - 1) * 64 + (xx - 1), f32);
    }
    tile[ty + i * 8][tx] = v;
  }
  __syncthreads();
#pragma unroll
  for (int i = 0; i < 4; i++) {
    int pp = p0 + ty + i * 8;
    if (pp >= 4356) continue;
    xbTp[((size_t)b * 4356 + pp) * 256 + c0 + tx] = f2h(tile[tx][ty + i * 8]);
  }
}

// ---- 3) weight reorders (fp16) ----
__global__ __launch_bounds__(256) void k_wq(const void* __restrict__ Wq,
                                            const int* __restrict__ flag,
                                            u16* __restrict__ WqB) {
  int idx = blockIdx.x * 256 + threadIdx.x;  // 256*2304
  int oc = idx / 2304, rem = idx - oc * 2304;
  int tap = rem >> 8, c = rem & 255;
  WqB[idx] = f2h(ldin(Wq, oc * 2304 + c * 9 + tap, flag[0]));
}
__global__ __launch_bounds__(256) void k_wkv(const void* __restrict__ Wk,
                                             const void* __restrict__ Wv,
                                             const int* __restrict__ flag,
                                             u16* __restrict__ WkvB) {
  int idx = blockIdx.x * 256 + threadIdx.x;  // 512*256
  int m = idx >> 8, c = idx & 255;
  float w = (m < 256) ? ldin(Wk, m * 256 + c, flag[0])
                      : ldin(Wv, (m - 256) * 256 + c, flag[0]);
  WkvB[idx] = f2h(w);
}

// ---- GEMM (fp16): C[M][N] = A[M][K] . Bt[N][K]^T  (R6 1-buf structure) ----
// Staging: global_load_lds width 16, XOR-swizzled packed LDS
// (LDS(r,c) = G(r, c^(r&7)); frag reads 2-way = free).
// IMC: B rows are implicit-im2col reads of xbTp (tap = tapBase + kt/256).
// EPI 0: fp32 store at C+cOff+b*zC.  EPI 1: fp32 atomicAdd (split-K partials).
// SWZ 1: tm banded per XCD (sw1 = tm tiles/XCD), batch b = blockIdx.y.
// SWZ 2: tn banded per XCD (sw1 = tm tiles, sw2 = tn tiles/XCD), kz = bz.
// SWZ 0: (bx,by) tiles; blockIdx.z = b*nSplit + kz (split-K, batched).
template <bool IMC, int EPI, int SWZ>
__global__ __launch_bounds__(256, 3) void gemm_bt(
    const u16* __restrict__ A, const u16* __restrict__ Bt, void* __restrict__ Cptr,
    int M, int N, int K, int ldB, int tapBase, long long cOff, int kChunk,
    int sw1, int sw2, int nSplit, long long zA, long long zB, long long zC) {
  __shared__ u16 lA[128 * 64];
  __shared__ u16 lB[128 * 64];
  int tm, tn, b = 0, kz = 0;
  if (SWZ == 1) {
    int lin = blockIdx.x, xcd = lin & 7, per = lin >> 3;
    tm = xcd * sw1 + (per % sw1);
    tn = per / sw1;
    b = blockIdx.y;
  } else if (SWZ == 2) {
    int lin = blockIdx.x, xcd = lin & 7, per = lin >> 3;
    tm = per % sw1;
    tn = xcd * sw2 + per / sw1;
    kz = blockIdx.z;
  } else {
    tm = blockIdx.x;
    tn = blockIdx.y;
    b = blockIdx.z / nSplit;
    kz = blockIdx.z % nSplit;
  }
  int k0 = 0, k1 = K;
  if (kChunk) {
    k0 = kz * kChunk;
    k1 = min(k0 + kChunk, K);
  }
  const int tid = threadIdx.x, wave = tid >> 6, lane = tid & 63;
  const int sr = lane >> 3;         // source row within 8-row issue group
  const int scw = (lane & 7) ^ sr;  // XOR-swizzled source chunk
  const int wm = (wave >> 1) * 64, wn = (wave & 1) * 64;
  const int r16 = lane & 15, q = lane >> 4;
  const u16* gA = A + (size_t)b * zA + (size_t)(tm * 128 + wave * 32 + sr) * K +
                  scw * 8;
  const u16* gB = nullptr;
  int pyI[4], pxI[4];
  size_t bOffI[4];
  if (IMC) {
#pragma unroll
    for (int i = 0; i < 4; i++) {
      int n = tn * 128 + wave * 32 + i * 8 + sr;  // global output pixel
      int bb = n >> 12, pix = n & 4095;
      pyI[i] = pix >> 6;
      pxI[i] = pix & 63;
      bOffI[i] = (size_t)bb * 4356;
    }
  } else {
    gB = Bt + (size_t)b * zB + (size_t)(tn * 128 + wave * 32 + sr) * ldB +
         scw * 8;
  }
  f32x4 acc[4][4] = {};

  for (int kt = k0; kt < k1; kt += 64) {
    int dy = 0, dx = 0, chunk = 0;
    if (IMC) {
      int tap = tapBase + (kt >> 8);
      chunk = kt & 255;
      dy = tap / 3;
      dx = tap - dy * 3;
    }
#pragma unroll
    for (int i = 0; i < 4; i++) {
      gld16(gA + (size_t)(i * 8) * K + kt, &lA[(wave * 32 + i * 8) * 64]);
      if (IMC) {
        int spix = (pyI[i] + dy) * 66 + pxI[i] + dx;
        gld16(Bt + (bOffI[i] + spix) * 256 + chunk + scw * 8,
              &lB[(wave * 32 + i * 8) * 64]);
      } else {
        gld16(gB + (size_t)(i * 8) * ldB + kt, &lB[(wave * 32 + i * 8) * 64]);
      }
    }
    __syncthreads();  // drains vmcnt (gld16 complete) + prior reads done
#pragma unroll
    for (int ks = 0; ks < 64; ks += 32) {
      f16x8 af[4], bfr[4];
#pragma unroll
      for (int f = 0; f < 4; f++) {
        int ma = wm + f * 16 + r16;
        int g = (ks >> 3) + q;
        af[f] = *(const f16x8*)&lA[ma * 64 + ((g ^ (ma & 7)) << 3)];
        int nb = wn + f * 16 + r16;
        bfr[f] = *(const f16x8*)&lB[nb * 64 + ((g ^ (nb & 7)) << 3)];
      }
#pragma unroll
      for (int fi = 0; fi < 4; fi++)
#pragma unroll
        for (int fj = 0; fj < 4; fj++)
          acc[fi][fj] = __builtin_amdgcn_mfma_f32_16x16x32_f16(
              af[fi], bfr[fj], acc[fi][fj], 0, 0, 0);
    }
    __syncthreads();  // LDS reads done before next iteration's gld16
  }

  const int colB = tn * 128 + wn + r16;
  const int rowB = tm * 128 + wm + q * 4;
  float* C = (float*)Cptr + cOff + (size_t)b * zC;
  if (EPI == 0) {
#pragma unroll
    for (int fi = 0; fi < 4; fi++)
#pragma unroll
      for (int r = 0; r < 4; r++) {
        size_t ro = (size_t)(rowB + fi * 16 + r) * N;
#pragma unroll
        for (int fj = 0; fj < 4; fj++) C[ro + colB + fj * 16] = acc[fi][fj][r];
      }
  } else {
#pragma unroll
    for (int fi = 0; fi < 4; fi++)
#pragma unroll
      for (int r = 0; r < 4; r++) {
        size_t ro = (size_t)(rowB + fi * 16 + r) * N;
#pragma unroll
        for (int fj = 0; fj < 4; fj++)
          atomicAdd(&C[ro + colB + fj * 16], acc[fi][fj][r]);
      }
  }
}

// ---- 5) BN stats (biases cancel; K/V border conv-value 0, count 17424) ----
__global__ __launch_bounds__(256) void k_stats(
    const float* __restrict__ bufQ, const float* __restrict__ bufKV,
    const void* __restrict__ gq, const void* __restrict__ betaq,
    const void* __restrict__ gk, const void* __restrict__ betak,
    const void* __restrict__ gv, const void* __restrict__ betav,
    const int* __restrict__ flag, float* __restrict__ nrm) {
  int f32 = flag[0];
  int ch = blockIdx.x, t = blockIdx.y, tid = threadIdx.x;
  const float* row = (t == 0) ? bufQ + (size_t)ch * 16384
                              : bufKV + (size_t)(t == 1 ? ch : 256 + ch) * 16384;
  float s = 0.f, ss = 0.f;
  for (int i = tid; i < 16384; i += 256) {
    float v = row[i];
    s += v;
    ss += v * v;
  }
#pragma unroll
  for (int off = 32; off; off >>= 1) {
    s += __shfl_down(s, off);
    ss += __shfl_down(ss, off);
  }
  __shared__ float ls[4], lss[4];
  if ((tid & 63) == 0) {
    ls[tid >> 6] = s;
    lss[tid >> 6] = ss;
  }
  __syncthreads();
  if (tid == 0) {
    s = ls[0] + ls[1] + ls[2] + ls[3];
    ss = lss[0] + lss[1] + lss[2] + lss[3];
    float cnt = (t == 0) ? 16384.f : 17424.f;
    float mean = s / cnt;
    float var = fmaxf(ss / cnt - mean * mean, 0.f);  // NaN-proof
    const void* g = (t == 0) ? gq : (t == 1 ? gk : gv);
    const void* be = (t == 0) ? betaq : (t == 1 ? betak : betav);
    float sc = ldin(g, ch, f32) * rsqrtf(var + 1e-5f);
    nrm[(t * 256 + ch) * 2] = sc;
    nrm[(t * 256 + ch) * 2 + 1] = ldin(be, ch, f32) - mean * sc;
  }
}

// ---- 6) normalize + transpose to fp16 (K=256 rows) ----
__global__ __launch_bounds__(256) void k_qTs(const float* __restrict__ bufQ,
                                             const float* __restrict__ nrm,
                                             u16* __restrict__ qTs) {
  __shared__ u16 th[32][33];
  int b = blockIdx.z, q0 = blockIdx.x * 32, c0 = blockIdx.y * 32;
  int tx = threadIdx.x, ty = threadIdx.y;
#pragma unroll
  for (int i = 0; i < 4; i++) {
    int c = c0 + ty + i * 8;
    float sc = nrm[c * 2], sh = nrm[c * 2 + 1];
    th[ty + i * 8][tx] =
        f2h(bufQ[(size_t)c * 16384 + b * 4096 + q0 + tx] * sc + sh);
  }
  __syncthreads();
#pragma unroll
  for (int i = 0; i < 4; i++)
    qTs[((size_t)b * 4096 + q0 + ty + i * 8) * 256 + c0 + tx] =
        th[tx][ty + i * 8];
}
__global__ __launch_bounds__(256) void k_kTs(const float* __restrict__ bufKV,
                                             const float* __restrict__ nrm,
                                             u16* __restrict__ kTs) {
  __shared__ u16 th[32][33];
  int b = blockIdx.z, k0 = blockIdx.x * 32, c0 = blockIdx.y * 32;
  int tx = threadIdx.x, ty = threadIdx.y;
#pragma unroll
  for (int i = 0; i < 4; i++) {
    int c = c0 + ty + i * 8;
    int kt = k0 + tx;
    float v = 0.f;
    if (kt < 4356) {
      float sc = nrm[(256 + c) * 2], sh = nrm[(256 + c) * 2 + 1];
      int yy = kt / 66, xx = kt - yy * 66;
      if (yy >= 1 && yy <= 64 && xx >= 1 && xx <= 64)
        v = bufKV[(size_t)c * 16384 + b * 4096 + (yy - 1) * 64 + (xx - 1)] * sc + sh;
      else
        v = sh;  // border: conv value 0
    }
    th[ty + i * 8][tx] = f2h(v);
  }
  __syncthreads();
#pragma unroll
  for (int i = 0; i < 4; i++)
    kTs[((size_t)b * 4480 + k0 + ty + i * 8) * 256 + c0 + tx] =
        th[tx][ty + i * 8];
}

// ---- 7) normalized V fp16, [b][c][4480], pads zero ----
__global__ __launch_bounds__(256) void k_vP(const float* __restrict__ bufKV,
                                            const float* __restrict__ nrm,
                                            u16* __restrict__ vP) {
  int b = blockIdx.z, ch = blockIdx.y;
  int kt = blockIdx.x * 256 + threadIdx.x;
  if (kt >= 4480) return;
  float v = 0.f;
  if (kt < 4356) {
    float sc = nrm[(512 + ch) * 2], sh = nrm[(512 + ch) * 2 + 1];
    int yy = kt / 66, xx = kt - yy * 66;
    if (yy >= 1 && yy <= 64 && xx >= 1 && xx <= 64)
      v = bufKV[(size_t)(256 + ch) * 16384 + b * 4096 + (yy - 1) * 64 + (xx - 1)] * sc + sh;
    else
      v = sh;
  }
  vP[((size_t)b * 256 + ch) * 4480 + kt] = f2h(v);
}

// ---- 8) softmax over kt: fp16 p written IN PLACE over St (ld 8960 u16) ----
__global__ __launch_bounds__(256) void k_softmax(float* __restrict__ St,
                                                 float* __restrict__ sumP) {
  __shared__ float row[4480];
  __shared__ float red[4], red2[4];
  int qt = blockIdx.x, tid = threadIdx.x;
  float* srow = St + (size_t)qt * 4480;
  float m = -3.0e38f;
  for (int kt = tid; kt < 4480; kt += 256) {
    float v = srow[kt];
    row[kt] = v;
    if (kt < 4356) m = fmaxf(m, v);
  }
#pragma unroll
  for (int off = 32; off; off >>= 1) m = fmaxf(m, __shfl_down(m, off));
  if ((tid & 63) == 0) red[tid >> 6] = m;
  __syncthreads();  // all srow reads complete before in-place writes
  m = fmaxf(fmaxf(red[0], red[1]), fmaxf(red[2], red[3]));
  u16* prow = (u16*)srow;
  float psum = 0.f;
  for (int kt = tid; kt < 4480; kt += 256) {
    u16 hb = 0;
    if (kt < 4356) {
      float p = __expf(fminf(row[kt] - m, 0.f));  // in (0,1], NaN-proof
      _Float16 h = (_Float16)p;
      hb = *(const u16*)&h;
      psum += (float)h;  // sum the rounded values for consistency
    }
    prow[kt] = hb;
  }
#pragma unroll
  for (int off = 32; off; off >>= 1) psum += __shfl_down(psum, off);
  if ((tid & 63) == 0) red2[tid >> 6] = psum;
  __syncthreads();
  if (tid == 0) sumP[qt] = red2[0] + red2[1] + red2[2] + red2[3];  // >= 1
}

// ---- 9) split-K support ----
__global__ __launch_bounds__(256) void k_zeroacc(float* __restrict__ accF) {
  accF[blockIdx.x * 256 + threadIdx.x] = 0.f;
}
__global__ __launch_bounds__(256) void k_final(const float* __restrict__ accF,
                                               const float* __restrict__ sumP,
                                               const int* __restrict__ flag,
                                               void* __restrict__ out,
                                               long long cOff) {
  int idx = blockIdx.x * 256 + threadIdx.x;       // [b_local][c][qt] flat
  int sidx = ((idx >> 20) << 12) | (idx & 4095);  // b_local*4096 + qt
  float v = accF[idx] / sumP[sidx];               // sumP >= 1
  v = (v == v) ? v : 0.f;  // NaN scrub: keep failures diagnostic
  if (flag[0])
    ((float*)out)[cOff + idx] = v;
  else
    ((u16*)out)[cOff + idx] = f2bf(v);
}

// ---------------------------------------------------------------------------
extern "C" void kernel_launch(void* const* d_in, const int* in_sizes, int n_in,
                              void* d_out, int out_size, void* d_ws, size_t ws_size,
                              hipStream_t stream) {
  const void* x = d_in[0];
  const void* Wq = d_in[1];
  const void* gq = d_in[3];
  const void* betaq = d_in[4];
  const void* Wk = d_in[5];
  const void* gk = d_in[7];
  const void* betak = d_in[8];
  const void* Wv = d_in[9];
  const void* gv = d_in[11];
  const void* betav = d_in[12];

  // 2-batch mega-phase mode requires 181,999,872 B (measured: ws < 337 MB).
  const bool ph2 = ws_size >= 181999872ull;
  char* ws = (char*)d_ws;
  int* flag = (int*)ws;                    // 256 B
  // Region A (conv phase; overlaid by St before attention):
  u16* xbTp = (u16*)(ws + 256);            //  8,921,088
  u16* WqB = (u16*)(ws + 8921344);         //  1,179,648
  u16* WkvB = (u16*)(ws + 10100992);       //    262,144
  float* bufQ = (float*)(ws + 10363136);   // 16,777,216
  float* bufKV = (float*)(ws + 27140352);  // 33,554,432 -> A ends 60,694,784
  // St overlays region A. Loop: 1 batch (73.4 MB). ph2: 2 (146.8 MB).
  float* St = (float*)(ws + 256);
  size_t rb = ph2 ? 146800896ull : 73400576ull;
  u16* qTs = (u16*)(ws + rb);                   //  8,388,608 (4*4096*256*2)
  u16* kTs = (u16*)(ws + rb + 8388608);         //  9,175,040 (4*4480*256*2)
  u16* vP = (u16*)(ws + rb + 17563648);         //  9,175,040
  float* nrm = (float*)(ws + rb + 26738688);    //      6,144
  float* sumP4 = (float*)(ws + rb + 26744832);  //     65,536
  float* accF = (float*)(ws + rb + 26810368);   // 4 MB loop / 8.4 MB ph2
  // totals: loop 104,405,248 B; ph2 181,999,872 B.

  dim3 b32x8(32, 8);
  k_detect<<<1, 256, 0, stream>>>((const unsigned*)Wq, flag);
  k_txp<<<dim3(137, 8, 4), b32x8, 0, stream>>>(x, flag, xbTp);
  k_wq<<<2304, 256, 0, stream>>>(Wq, flag, WqB);
  k_wkv<<<512, 256, 0, stream>>>(Wk, Wv, flag, WkvB);
  // conv3x3: K=2304 split-K x3 (chunk 768) into zeroed bufQ; 768 blocks.
  k_zeroacc<<<16384, 256, 0, stream>>>(bufQ);
  gemm_bt<true, 1, 2><<<dim3(256, 1, 3), 256, 0, stream>>>(
      WqB, xbTp, bufQ, 256, 16384, 2304, 0, 0, 0, 768, 2, 16, 1, 0, 0, 0);
  // conv1x1: K=256; grid 512 = 8 XCD x (4 tm x 16 tn-band)
  gemm_bt<true, 0, 2><<<512, 256, 0, stream>>>(
      WkvB, xbTp, bufKV, 512, 16384, 256, 0, 4, 0, 0, 4, 16, 1, 0, 0, 0);
  k_stats<<<dim3(256, 3), 256, 0, stream>>>(bufQ, bufKV, gq, betaq, gk, betak,
                                            gv, betav, flag, nrm);
  k_qTs<<<dim3(128, 8, 4), b32x8, 0, stream>>>(bufQ, nrm, qTs);
  k_kTs<<<dim3(140, 8, 4), b32x8, 0, stream>>>(bufKV, nrm, kTs);
  k_vP<<<dim3(18, 256, 4), 256, 0, stream>>>(bufKV, nrm, vP);

  if (ph2) {
    for (int p = 0; p < 2; p++) {  // batches 2p, 2p+1
      gemm_bt<false, 0, 1><<<dim3(1120, 2), 256, 0, stream>>>(
          qTs + (size_t)(2 * p) * 4096 * 256, kTs + (size_t)(2 * p) * 4480 * 256,
          St, 4096, 4480, 256, 256, 0, 0, 0, 4, 0, 1, 4096LL * 256,
          4480LL * 256, 4096LL * 4480);
      k_softmax<<<8192, 256, 0, stream>>>(St, sumP4 + p * 8192);
      k_zeroacc<<<8192, 256, 0, stream>>>(accF);
      // PV: 2 batches, split-K x5 (chunk 896): grid (2,32,10)
      gemm_bt<false, 1, 0><<<dim3(2, 32, 10), 256, 0, stream>>>(
          vP + (size_t)(2 * p) * 256 * 4480, (const u16*)St, accF, 256, 4096,
          4480, 8960, 0, 0, 896, 0, 0, 5, 256LL * 4480, 4096LL * 8960,
          256LL * 4096);
      k_final<<<8192, 256, 0, stream>>>(accF, sumP4 + p * 8192, flag, d_out,
                                        (long long)p * 2097152);
    }
  } else {
    for (int b = 0; b < 4; b++) {
      gemm_bt<false, 0, 1><<<dim3(1120, 1), 256, 0, stream>>>(
          qTs + (size_t)b * 4096 * 256, kTs + (size_t)b * 4480 * 256, St, 4096,
          4480, 256, 256, 0, 0, 0, 4, 0, 1, 0, 0, 0);
      k_softmax<<<4096, 256, 0, stream>>>(St, sumP4 + b * 4096);
      k_zeroacc<<<4096, 256, 0, stream>>>(accF);
      gemm_bt<false, 1, 0><<<dim3(2, 32, 7), 256, 0, stream>>>(
          vP + (size_t)b * 256 * 4480, (const u16*)St, accF, 256, 4096, 4480,
          8960, 0, 0, 640, 0, 0, 7, 0, 0, 0);
      k_final<<<4096, 256, 0, stream>>>(accF, sumP4 + (size_t)b * 4096, flag,
                                        d_out, (long long)b * 1048576);
    }
  }
}